// Round 6
// baseline (49.143 us; speedup 1.0000x reference)
//
#include <hip/hip_runtime.h>

// LocallyConnected2d: out[b,o,ho,wo] = bias[o,ho,wo]
//   + sum_{c,ki,kj} x[b,c,ho+ki,wo+kj] * w[o,c,ho,wo,ki*3+kj]
//
// Round-6: barrier-free main loop (r5's per-cc __syncthreads was a block-wide
// fix for a wave-local hazard; its vmcnt(0) drain gated everyone on the
// just-issued HBM stage -> m97-style ~40% stall).
//  - All 4 weight-row stages issued UPFRONT into 4 per-wave LDS buffers via
//    global_load_lds (wave-local, linear dest).
//  - Body cc waits s_waitcnt vmcnt(9*(3-cc)): in-order completion guarantees
//    stage(cc) landed while later stages stay in flight. No barriers.
//  - lane (q,l): l=lane&15 owns wo=4l..4l+3 (f4+f2 x window, no cross-lane);
//    q=lane>>4 owns b=2q,2q+1. Weights: 9x ds_read_b128 per cc (16B aligned).
//  - Epilogue: stash partials per-wave, ONE __syncthreads, cross-wave reduce,
//    bias add, coalesced store.

#define BB 8
#define CC 16
#define HH 64
#define WW 64
#define OO 32
#define HO 62
#define WO 62
#define NLOC (HO * WO)    // 3844
#define TOTAL (OO * NLOC) // 123008

typedef float f4 __attribute__((ext_vector_type(4)));
typedef float f2 __attribute__((ext_vector_type(2)));

__device__ __forceinline__ void async_f32_to_lds(const float* g, float* l) {
  __builtin_amdgcn_global_load_lds((const __attribute__((address_space(1))) void*)g,
                                   (__attribute__((address_space(3))) void*)l,
                                   4, 0, 0);
}

__global__ __launch_bounds__(256, 4) void lc2d_kernel(
    const float* __restrict__ x, const float* __restrict__ weight,
    const float* __restrict__ bias, float* __restrict__ out) {
  // 4 waves x 4 c-buffers x 576 floats = 36864 B
  __shared__ __align__(16) float smem[4 * 4 * 576];

  const int tid  = threadIdx.x;
  const int lane = tid & 63;
  const int wave = tid >> 6;
  const int l = lane & 15;   // wo-group: wo = 4l..4l+3
  const int q = lane >> 4;   // b-group:  b  = 2q, 2q+1
  const int ho = blockIdx.x % HO;
  const int o  = blockIdx.x / HO;

  float* bufs = smem + wave * 2304;
  const int colbase = 4 * l;
  const int f2off = (l < 15) ? 4 : -4;  // l=15: dummy in-bounds read, discarded

  const float* wbase = weight + (size_t)(o * CC + wave * 4) * (NLOC * 9)
                              + (size_t)ho * (WO * 9);

  // ---- issue ALL four stage streams upfront (36 glds, wave-local) ----
#pragma unroll
  for (int cc = 0; cc < 4; ++cc) {
    const float* wg = wbase + (size_t)cc * (NLOC * 9);
    float* dst = bufs + cc * 576;
#pragma unroll
    for (int j = 0; j < 9; ++j)
      if (j * 64 + lane < WO * 9)
        async_f32_to_lds(wg + j * 64 + lane, dst + j * 64);
  }

  f4 acc[2];
  acc[0] = (f4)0.f;
  acc[1] = (f4)0.f;

  // ---- bodies: wait only for the buffer being read; later stages in flight.
  // vmcnt(N) sound: completion is in-order, <=N outstanding => stage(cc) done.
#define BODY(cc, WAITSTR)                                                     \
  {                                                                           \
    asm volatile("s_waitcnt " WAITSTR ::: "memory");                          \
    const float* cur = bufs + (cc) * 576;                                     \
    f4 wq[9];                                                                 \
    _Pragma("unroll")                                                         \
    for (int k = 0; k < 9; ++k) wq[k] = *(const f4*)(cur + 36 * l + 4 * k);   \
    const float* xc = x + (size_t)(wave * 4 + (cc)) * (HH * WW)               \
                        + (size_t)ho * WW + colbase;                          \
    _Pragma("unroll")                                                         \
    for (int bo = 0; bo < 2; ++bo) {                                          \
      const float* xb = xc + (size_t)(2 * q + bo) * (CC * HH * WW);           \
      f4 v4[3]; f2 v2[3];                                                     \
      _Pragma("unroll")                                                       \
      for (int r = 0; r < 3; ++r) {                                           \
        v4[r] = *(const f4*)(xb + r * WW);                                    \
        v2[r] = *(const f2*)(xb + r * WW + f2off);                            \
      }                                                                       \
      _Pragma("unroll")                                                       \
      for (int w4 = 0; w4 < 4; ++w4) {                                        \
        float s = 0.f;                                                        \
        _Pragma("unroll")                                                     \
        for (int r = 0; r < 3; ++r) {                                         \
          _Pragma("unroll")                                                   \
          for (int j = 0; j < 3; ++j) {                                       \
            const int e = w4 + j;                /* 0..5, compile-time */     \
            const int wi = w4 * 9 + r * 3 + j;   /* 0..35, compile-time */    \
            const float xv = (e < 4) ? v4[r][e] : v2[r][e - 4];               \
            s += xv * wq[wi >> 2][wi & 3];                                    \
          }                                                                   \
        }                                                                     \
        acc[bo][w4] += s;                                                     \
      }                                                                       \
    }                                                                         \
  }

  BODY(0, "vmcnt(27)")
  BODY(1, "vmcnt(18)")
  BODY(2, "vmcnt(9)")
  BODY(3, "vmcnt(0)")
#undef BODY

  // ---- stash partials into this wave's region (aliases buf0; the ds_reads
  // that staged it are retired — their data is in acc) ----
#pragma unroll
  for (int bo = 0; bo < 2; ++bo)
    *(f4*)(bufs + (2 * q + bo) * 64 + colbase) = acc[bo];
  __syncthreads();  // the only block-wide barrier

  // ---- reduce 4 wave-partials, add bias, coalesced store ----
  for (int p = tid; p < 512; p += 256) {
    const int b  = p >> 6;
    const int wo = p & 63;
    if (wo < WO) {
      float s = smem[0 * 2304 + p] + smem[1 * 2304 + p]
              + smem[2 * 2304 + p] + smem[3 * 2304 + p];
      const int loc = o * NLOC + ho * WO + wo;
      out[(size_t)b * TOTAL + loc] = s + bias[loc];
    }
  }
}

extern "C" void kernel_launch(void* const* d_in, const int* in_sizes, int n_in,
                              void* d_out, int out_size, void* d_ws, size_t ws_size,
                              hipStream_t stream) {
  const float* x = (const float*)d_in[0];
  const float* w = (const float*)d_in[1];
  const float* bias = (const float*)d_in[2];
  float* out = (float*)d_out;

  hipLaunchKernelGGL(lc2d_kernel, dim3(OO * HO), dim3(256), 0, stream,
                     x, w, bias, out);
}

// Round 7
// 26.598 us; speedup vs baseline: 1.8476x; 1.8476x over previous
//
#include <hip/hip_runtime.h>

// LocallyConnected2d: out[b,o,ho,wo] = bias[o,ho,wo]
//   + sum_{c,ki,kj} x[b,c,ho+ki,wo+kj] * w[o,c,ho,wo,ki*3+kj]
//
// Round-7 = Round-5 (26.6us, passing) with ONLY the sync mechanism changed:
//  - per-wave double-buffered weight staging via global_load_lds (unchanged)
//  - in-loop __syncthreads() (block-wide vmcnt(0) drain for a wave-local
//    hazard) replaced by per-wave counted s_waitcnt vmcnt(9)/(0):
//      body cc: issue stage(cc+1) -> wait vmcnt(9). Outstanding there =
//      stage(cc) + stage(cc+1) only (earlier x-loads retired: the FMAs that
//      consumed them issued already, in-order issue). <=9 left => stage(cc)
//      landed, stage(cc+1) still in flight. Last body: vmcnt(0).
//    sched_barrier(0) fences pin compiler motion (rule #18); NO asm memory
//    clobbers (r6's clobbers caused scratch spills: WRITE_SIZE 3.8->67.7MB).
//  - WAR on buffer reuse is sound: in-order issue means body cc-1's wq
//    ds_reads returned before any body-cc instruction (incl. glds) issues.
//  - epilogue unchanged: stash partials, ONE __syncthreads, reduce, store.

#define BB 8
#define CC 16
#define HH 64
#define WW 64
#define OO 32
#define HO 62
#define WO 62
#define NLOC (HO * WO)    // 3844
#define TOTAL (OO * NLOC) // 123008

typedef float f4 __attribute__((ext_vector_type(4)));
typedef float f2 __attribute__((ext_vector_type(2)));

__device__ __forceinline__ void async_f32_to_lds(const float* g, float* l) {
  __builtin_amdgcn_global_load_lds((const __attribute__((address_space(1))) void*)g,
                                   (__attribute__((address_space(3))) void*)l,
                                   4, 0, 0);
}

__global__ __launch_bounds__(256) void lc2d_kernel(
    const float* __restrict__ x, const float* __restrict__ weight,
    const float* __restrict__ bias, float* __restrict__ out) {
  // per wave: two 576-float weight buffers; buf0 reused for partial stash
  __shared__ __align__(16) float smem[4 * 2 * 576];

  const int tid  = threadIdx.x;
  const int lane = tid & 63;
  const int wave = tid >> 6;
  const int l = lane & 15;   // wo-group: wo = 4l..4l+3
  const int q = lane >> 4;   // b-group:  b  = 2q, 2q+1
  const int ho = blockIdx.x % HO;
  const int o  = blockIdx.x / HO;

  float* buf0 = smem + wave * 1152;
  float* buf1 = buf0 + 576;

  const int colbase = 4 * l;
  const int f2off = (l < 15) ? 4 : -4;  // l=15: dummy in-bounds read, discarded

  const float* wbase = weight + (size_t)(o * CC + wave * 4) * (NLOC * 9)
                              + (size_t)ho * (WO * 9);

  // ---- prologue: stage cc=0 into buf0 ----
#pragma unroll
  for (int j = 0; j < 9; ++j)
    if (j * 64 + lane < WO * 9)
      async_f32_to_lds(wbase + j * 64 + lane, buf0 + j * 64);

  f4 acc[2];
  acc[0] = (f4)0.f;
  acc[1] = (f4)0.f;

  float* cur = buf0;
  float* nxt = buf1;

#pragma unroll
  for (int cc = 0; cc < 4; ++cc) {
    __builtin_amdgcn_sched_barrier(0);  // body boundary: nothing crosses
    if (cc < 3) {
      // issue stage(cc+1) into the other buffer (stays in flight past wait)
      const float* wg = wbase + (size_t)(cc + 1) * (NLOC * 9);
#pragma unroll
      for (int j = 0; j < 9; ++j)
        if (j * 64 + lane < WO * 9)
          async_f32_to_lds(wg + j * 64 + lane, nxt + j * 64);
      __builtin_amdgcn_sched_barrier(0);
      asm volatile("s_waitcnt vmcnt(9)");  // stage(cc) landed; cc+1 in flight
      __builtin_amdgcn_sched_barrier(0);
    } else {
      asm volatile("s_waitcnt vmcnt(0)");  // last: all DMA landed (also
      __builtin_amdgcn_sched_barrier(0);   // protects the stash overwrite)
    }

    // ---- 36 weights (wo=4l..4l+3 x k=0..8): 9x ds_read_b128 ----
    f4 wq[9];
#pragma unroll
    for (int k = 0; k < 9; ++k)
      wq[k] = *(const f4*)(cur + 36 * l + 4 * k);

    const int c = wave * 4 + cc;
#pragma unroll
    for (int bo = 0; bo < 2; ++bo) {
      const float* xb = x + ((size_t)(2 * q + bo) * CC + c) * (HH * WW)
                          + (size_t)ho * WW + colbase;
      f4 v4[3];
      f2 v2[3];
#pragma unroll
      for (int r = 0; r < 3; ++r) {
        v4[r] = *(const f4*)(xb + r * WW);
        v2[r] = *(const f2*)(xb + r * WW + f2off);
      }
#pragma unroll
      for (int w4 = 0; w4 < 4; ++w4) {
        float s = 0.f;
#pragma unroll
        for (int r = 0; r < 3; ++r) {
#pragma unroll
          for (int j = 0; j < 3; ++j) {
            const int e = w4 + j;                 // 0..5, compile-time
            const int wi = w4 * 9 + r * 3 + j;    // 0..35, compile-time
            const float xv = (e < 4) ? v4[r][e] : v2[r][e - 4];
            s += xv * wq[wi >> 2][wi & 3];
          }
        }
        acc[bo][w4] += s;
      }
    }
    float* t = cur; cur = nxt; nxt = t;
  }

  // ---- stash partials into this wave's buf0 (all DMA drained by vmcnt(0)) ----
#pragma unroll
  for (int bo = 0; bo < 2; ++bo)
    *(f4*)(buf0 + (2 * q + bo) * 64 + colbase) = acc[bo];
  __syncthreads();  // the only block-wide barrier

  // ---- reduce 4 wave-partials, add bias, coalesced store ----
  for (int p = tid; p < 512; p += 256) {
    const int b  = p >> 6;
    const int wo = p & 63;
    if (wo < WO) {
      float s = smem[0 * 1152 + p] + smem[1 * 1152 + p]
              + smem[2 * 1152 + p] + smem[3 * 1152 + p];
      const int loc = o * NLOC + ho * WO + wo;
      out[(size_t)b * TOTAL + loc] = s + bias[loc];
    }
  }
}

extern "C" void kernel_launch(void* const* d_in, const int* in_sizes, int n_in,
                              void* d_out, int out_size, void* d_ws, size_t ws_size,
                              hipStream_t stream) {
  const float* x = (const float*)d_in[0];
  const float* w = (const float*)d_in[1];
  const float* bias = (const float*)d_in[2];
  float* out = (float*)d_out;

  hipLaunchKernelGGL(lc2d_kernel, dim3(OO * HO), dim3(256), 0, stream,
                     x, w, bias, out);
}